// Round 1
// 391.521 us; speedup vs baseline: 1.0354x; 1.0354x over previous
//
#include <hip/hip_runtime.h>

// Problem dims (fixed by the reference)
#define R_DIM 64
#define C_DIM 1024
#define B_DIM 2
#define E_DIM 256
#define Q_DIM 256
#define H_DIM 8
#define D_DIM 32
#define ROW_STRIDE ((size_t)C_DIM * B_DIM * E_DIM) /* 524288 floats between r rows */
#define OUT_MAIN ((size_t)R_DIM * C_DIM * B_DIM * E_DIM) /* 33554432 */

typedef short bf16x8 __attribute__((ext_vector_type(8)));
typedef float f32x4 __attribute__((ext_vector_type(4)));

__device__ __forceinline__ unsigned short f2bf(float x) {
  unsigned int u = __builtin_bit_cast(unsigned int, x);
  u += 0x7FFFu + ((u >> 16) & 1u);
  return (unsigned short)(u >> 16);
}

// ---------------------------------------------------------------------------
// prep_q: q[n,e] = (query @ Wq.T + bq)*0.125   (2 blocks x 256 threads)
// ---------------------------------------------------------------------------
__global__ void prep_q(const float* __restrict__ query, const float* __restrict__ Wq,
                       const float* __restrict__ bq, float* __restrict__ q_out) {
  int idx = blockIdx.x * 256 + threadIdx.x; // 0..511
  int n = idx >> 8, e = idx & 255;
  const float4* qr = (const float4*)(query + (size_t)n * Q_DIM);
  const float4* wr = (const float4*)(Wq + (size_t)e * Q_DIM);
  float s = bq[e];
#pragma unroll 8
  for (int k = 0; k < Q_DIM / 4; k++) {
    float4 a = qr[k], b = wr[k];
    s += a.x * b.x + a.y * b.y + a.z * b.z + a.w * b.w;
  }
  q_out[idx] = s * 0.125f; // D^-0.5 / sqrt(B) = 1/8
}

// ---------------------------------------------------------------------------
// prep_w_pack: blocks 0..15 = prep_w (w[h,n,e], bterm), blocks 16..79 = prepack
// (Wv/Wo fp32 -> bf16 MFMA B-fragment order).
// ---------------------------------------------------------------------------
__global__ void prep_w_pack(const float* __restrict__ q, const float* __restrict__ Wk,
                            const float* __restrict__ bk, float* __restrict__ w_out,
                            float* __restrict__ bterm_out,
                            const float* __restrict__ Wv, const float* __restrict__ Wo,
                            unsigned short* __restrict__ B1p, unsigned short* __restrict__ B2p) {
  if (blockIdx.x < 16) {
    int idx = blockIdx.x * 256 + threadIdx.x; // 0..4095  = ((h*2+n)*256 + e)
    int e2 = idx & 255;
    int hn = idx >> 8;
    int n = hn & 1, h = hn >> 1;
    float s = 0.f;
#pragma unroll
    for (int d = 0; d < D_DIM; d++)
      s += q[n * E_DIM + h * D_DIM + d] * Wk[(h * D_DIM + d) * E_DIM + e2];
    w_out[idx] = s;
    if (idx < H_DIM * B_DIM) {
      int nn = idx & 1, hh = idx >> 1;
      float sb = 0.f;
#pragma unroll
      for (int d = 0; d < D_DIM; d++)
        sb += q[nn * E_DIM + hh * D_DIM + d] * bk[hh * D_DIM + d];
      bterm_out[idx] = sb;
    }
  } else {
    int gidx = (blockIdx.x - 16) * 256 + threadIdx.x; // 0..16383
    const float* src = (gidx < 8192) ? Wv : Wo;
    unsigned short* dst = (gidx < 8192) ? B1p : B2p;
    int li = gidx & 8191;
    int lane = li & 63;
    int pk = li >> 6;
    int ntile = pk >> 3, kstep = pk & 7;
    int row = ntile * 16 + (lane & 15);
    int col0 = kstep * 32 + (lane >> 4) * 8;
    for (int jj = 0; jj < 8; jj++)
      dst[li * 8 + jj] = f2bf(src[row * E_DIM + col0 + jj]);
  }
}

// ---------------------------------------------------------------------------
// scores: block per (j,n). Wave wv reads rows r≡wv (mod 4) as float4/lane
// (1KB contiguous per row), cross-wave LDS reduce, then per-head dot + shuffle.
// ---------------------------------------------------------------------------
__global__ void scores_kernel(const float* __restrict__ key, const float* __restrict__ w,
                              const float* __restrict__ bterm, float* __restrict__ scores) {
  const int bid = blockIdx.x;
  const int j = bid >> 1, n = bid & 1;
  const int t = threadIdx.x;
  const int lane = t & 63, wv = t >> 6;

  const float4* kp = (const float4*)(key + ((size_t)j * B_DIM + n) * E_DIM) + lane;
  float4 ks4 = {0.f, 0.f, 0.f, 0.f};
#pragma unroll
  for (int r = wv; r < R_DIM; r += 4) {
    float4 v = kp[(size_t)r * (ROW_STRIDE / 4)];
    ks4.x += v.x; ks4.y += v.y; ks4.z += v.z; ks4.w += v.w;
  }
  __shared__ float red4[4][E_DIM];
  *(float4*)(&red4[wv][lane * 4]) = ks4;
  __syncthreads();
  float ks = red4[0][t] + red4[1][t] + red4[2][t] + red4[3][t];

  __shared__ float red[H_DIM][4];
  for (int h = 0; h < H_DIM; h++) {
    float p = ks * w[(h * B_DIM + n) * E_DIM + t];
    for (int off = 32; off > 0; off >>= 1) p += __shfl_down(p, off, 64);
    if (lane == 0) red[h][wv] = p;
  }
  __syncthreads();
  if (t < H_DIM) {
    float s = red[t][0] + red[t][1] + red[t][2] + red[t][3] +
              (float)R_DIM * bterm[t * B_DIM + n];
    scores[(t * B_DIM + n) * C_DIM + j] = s;
  }
}

// ---------------------------------------------------------------------------
// softmax over C per (h,n). Writes probs to ws AND to d_out tail.
// ---------------------------------------------------------------------------
__global__ void softmax_kernel(const float* __restrict__ scores, float* __restrict__ probs,
                               float* __restrict__ probs_out) {
  const int hn = blockIdx.x;
  const int t = threadIdx.x;
  const float* s = scores + (size_t)hn * C_DIM;
  float v[4];
  float mx = -1e30f;
  for (int i = 0; i < 4; i++) {
    v[i] = s[t + i * 256];
    mx = fmaxf(mx, v[i]);
  }
  __shared__ float sm[4];
  const int lane = t & 63, wv = t >> 6;
  for (int off = 32; off > 0; off >>= 1) mx = fmaxf(mx, __shfl_down(mx, off, 64));
  if (lane == 0) sm[wv] = mx;
  __syncthreads();
  mx = fmaxf(fmaxf(sm[0], sm[1]), fmaxf(sm[2], sm[3]));
  float sum = 0.f;
  for (int i = 0; i < 4; i++) {
    v[i] = expf(v[i] - mx);
    sum += v[i];
  }
  for (int off = 32; off > 0; off >>= 1) sum += __shfl_down(sum, off, 64);
  __syncthreads();
  if (lane == 0) sm[wv] = sum;
  __syncthreads();
  sum = sm[0] + sm[1] + sm[2] + sm[3];
  float inv = 1.0f / sum;
  for (int i = 0; i < 4; i++) {
    float p = v[i] * inv;
    probs[(size_t)hn * C_DIM + t + i * 256] = p;
    probs_out[(size_t)hn * C_DIM + t + i * 256] = p;
  }
}

// ---------------------------------------------------------------------------
// fused_pv: block per (j,n), 512 threads = 8 waves. Wave wv owns cols
// [wv*32, wv*32+32) = exactly head wv. Tile uses stride 256 (no pad) with a
// row-dependent column ROTATION (col' = (col + 16*((row>>2)&3)) & 255 shorts):
//  - staging writes: rotation of contiguous 512B row -> conflict-free
//  - b128 A-frag reads: 16B-aligned, 8 req/bank (minimum) -> conflict-free
//  - epilogue1 bf16 transpose writes: 4 quads -> 4 distinct bank octets
//    (was 4-way conflicted with the 264-stride pad) -> conflict-free
// LDS = exactly 32KB (tile and otile alias), 3-4 blocks/CU.
// ---------------------------------------------------------------------------
union __align__(16) SmemT {
  unsigned short tile[64 * 256]; // 32768 B (staging + transpose, bf16, rotated)
  float otile[32 * 256];         // 32768 B (output half-tile, fp32, rotated)
};

__global__ __launch_bounds__(512, 6) void fused_pv(
    const float* __restrict__ value, const unsigned short* __restrict__ B1p,
    const unsigned short* __restrict__ B2p, const float* __restrict__ bv,
    const float* __restrict__ bo, const float* __restrict__ probs,
    float* __restrict__ out) {
  __shared__ SmemT sm;
  const int bid = blockIdx.x;
  const int j = bid >> 1, n = bid & 1;
  const int t = threadIdx.x;
  const int lane = t & 63;
  const int wv = t >> 6;      // 0..7
  const int l15 = lane & 15;
  const int quad = lane >> 4;

  // --- stage value[*, j, n, :] -> bf16 LDS (rotated layout) ---
  const float* vbase = value + ((size_t)j * B_DIM + n) * E_DIM;
#pragma unroll
  for (int row = wv; row < 64; row += 8) {
    const float4 v4 = *(((const float4*)(vbase + (size_t)row * ROW_STRIDE)) + lane);
    ushort4 u;
    u.x = f2bf(v4.x); u.y = f2bf(v4.y); u.z = f2bf(v4.z); u.w = f2bf(v4.w);
    const int col = (lane * 4 + ((row & 12) << 2)) & 255;
    *(ushort4*)(&sm.tile[row * 256 + col]) = u;
  }
  __syncthreads();

  f32x4 acc[4][2]; // [m-tile][n-tile]
  const f32x4 zero = {0.f, 0.f, 0.f, 0.f};
#pragma unroll
  for (int mt = 0; mt < 4; mt++)
#pragma unroll
    for (int nt = 0; nt < 2; nt++) acc[mt][nt] = zero;

  const int arot = (l15 & 12) << 2; // A-frag rotation: 16*((row>>2)&3), row=mt*16+l15

  // --- GEMM1: v = val @ Wv.T ---
#pragma unroll
  for (int ks = 0; ks < 8; ks++) {
    bf16x8 a[4], b[2];
#pragma unroll
    for (int mt = 0; mt < 4; mt++)
      a[mt] = *(const bf16x8*)(&sm.tile[(mt * 16 + l15) * 256 +
                                        ((ks * 32 + quad * 8 + arot) & 255)]);
#pragma unroll
    for (int nt = 0; nt < 2; nt++)
      b[nt] = ((const bf16x8*)B1p)[((wv * 2 + nt) * 8 + ks) * 64 + lane];
#pragma unroll
    for (int mt = 0; mt < 4; mt++)
#pragma unroll
      for (int nt = 0; nt < 2; nt++)
        acc[mt][nt] = __builtin_amdgcn_mfma_f32_16x16x32_bf16(a[mt], b[nt], acc[mt][nt], 0, 0, 0);
  }

  // probs for this wave's head (cols wv*32..wv*32+31 -> head wv)
  const float p = probs[((size_t)wv * B_DIM + n) * C_DIM + j];

  __syncthreads(); // all GEMM1 LDS reads done before overwrite
  // --- epilogue1: +bv, *probs(head), bf16, write back transposed (rotated) ---
  const int erot = quad << 4; // 16*((row>>2)&3) with row = mt*16 + quad*4 + i
#pragma unroll
  for (int nt = 0; nt < 2; nt++) {
    const int e = wv * 32 + nt * 16 + l15;
    const float bias = bv[e];
    const int ecol = (e + erot) & 255;
#pragma unroll
    for (int mt = 0; mt < 4; mt++) {
#pragma unroll
      for (int i = 0; i < 4; i++) {
        int row = mt * 16 + quad * 4 + i;
        sm.tile[row * 256 + ecol] = f2bf((acc[mt][nt][i] + bias) * p);
      }
      acc[mt][nt] = zero;
    }
  }
  __syncthreads();

  // --- GEMM2: out = vs @ Wo.T ---
#pragma unroll
  for (int ks = 0; ks < 8; ks++) {
    bf16x8 a[4], b[2];
#pragma unroll
    for (int mt = 0; mt < 4; mt++)
      a[mt] = *(const bf16x8*)(&sm.tile[(mt * 16 + l15) * 256 +
                                        ((ks * 32 + quad * 8 + arot) & 255)]);
#pragma unroll
    for (int nt = 0; nt < 2; nt++)
      b[nt] = ((const bf16x8*)B2p)[((wv * 2 + nt) * 8 + ks) * 64 + lane];
#pragma unroll
    for (int mt = 0; mt < 4; mt++)
#pragma unroll
      for (int nt = 0; nt < 2; nt++)
        acc[mt][nt] = __builtin_amdgcn_mfma_f32_16x16x32_bf16(a[mt], b[nt], acc[mt][nt], 0, 0, 0);
  }

  // --- epilogue2: +bo, fp32 LDS half-tile (rotated) -> 1KB-contiguous stores ---
  float* obase = out + ((size_t)j * B_DIM + n) * E_DIM;
  const int orot = quad << 3; // 8*((lr>>2)&3) with lr = (mt-2h2)*16 + quad*4 + i
#pragma unroll
  for (int h2 = 0; h2 < 2; h2++) {
    __syncthreads(); // GEMM2 tile reads (h2=0) / prior otile ds_reads (h2=1) done
#pragma unroll
    for (int mt = 2 * h2; mt < 2 * h2 + 2; mt++) {
#pragma unroll
      for (int nt = 0; nt < 2; nt++) {
        const int e = wv * 32 + nt * 16 + l15;
        const float bias = bo[e];
        const int ecol = (e + orot) & 255;
#pragma unroll
        for (int i = 0; i < 4; i++) {
          int lr = (mt - 2 * h2) * 16 + quad * 4 + i;
          sm.otile[lr * 256 + ecol] = acc[mt][nt][i] + bias;
        }
      }
    }
    __syncthreads();
#pragma unroll
    for (int it = 0; it < 4; it++) {
      int idx = it * 512 + t;
      int lr = idx >> 6;   // 0..31
      int f4 = idx & 63;   // float4 index within row
      int col = (f4 * 4 + ((lr & 12) << 1)) & 255;
      float4 v = *(const float4*)(&sm.otile[lr * 256 + col]);
      *(float4*)(&obase[(size_t)(h2 * 32 + lr) * ROW_STRIDE + f4 * 4]) = v;
    }
  }
}

// ---------------------------------------------------------------------------
extern "C" void kernel_launch(void* const* d_in, const int* in_sizes, int n_in,
                              void* d_out, int out_size, void* d_ws, size_t ws_size,
                              hipStream_t stream) {
  const float* query = (const float*)d_in[0];
  const float* key   = (const float*)d_in[1];
  const float* value = (const float*)d_in[2];
  const float* Wq = (const float*)d_in[3];
  const float* bq = (const float*)d_in[4];
  const float* Wk = (const float*)d_in[5];
  const float* bk = (const float*)d_in[6];
  const float* Wv = (const float*)d_in[7];
  const float* bv = (const float*)d_in[8];
  const float* Wo = (const float*)d_in[9];
  const float* bo = (const float*)d_in[10];
  float* out = (float*)d_out;

  // workspace (floats): w[4096] | bterm[16] | scores[16384] | probs[16384]
  // then bf16: B1p (128KB) | B2p (128KB).  q (512 floats) aliases scores.
  float* ws_f = (float*)d_ws;
  float* w_ = ws_f;
  float* bterm_ = ws_f + 4096;
  float* scores_ = ws_f + 4112;
  float* q_ = scores_; // alias: q dead before scores_kernel writes
  float* probs_ = ws_f + 20496;
  unsigned short* B1p = (unsigned short*)((char*)d_ws + 147520);
  unsigned short* B2p = (unsigned short*)((char*)d_ws + 147520 + 131072);

  prep_q<<<dim3(2), dim3(256), 0, stream>>>(query, Wq, bq, q_);
  prep_w_pack<<<dim3(80), dim3(256), 0, stream>>>(q_, Wk, bk, w_, bterm_, Wv, Wo, B1p, B2p);
  scores_kernel<<<dim3(C_DIM * B_DIM), dim3(256), 0, stream>>>(key, w_, bterm_, scores_);
  softmax_kernel<<<dim3(H_DIM * B_DIM), dim3(256), 0, stream>>>(scores_, probs_,
                                                                out + OUT_MAIN);
  fused_pv<<<dim3(C_DIM * B_DIM), dim3(512), 0, stream>>>(value, B1p, B2p, bv, bo,
                                                          probs_, out);
}